// Round 5
// baseline (238.999 us; speedup 1.0000x reference)
//
#include <hip/hip_runtime.h>

#define EPS 1e-8f
#define LN_EPS 1e-5f
#define NROWS 8192
#define SLEN 4096
#define PROBS_OFF 2097152   // 8192*256

typedef __attribute__((ext_vector_type(8))) short bf16x8;
typedef __attribute__((ext_vector_type(4))) float f32x4;

__device__ __forceinline__ short f2bf(float f) {
    unsigned u = __float_as_uint(f);
    unsigned r = (u + 0x7FFFu + ((u >> 16) & 1u)) >> 16;  // RNE
    return (short)r;
}

// ---------------- K1: wave-per-row, pure-register, zero-LDS ----------------
// Lane l owns elements [64l, 64l+64) as x[64] filled with CONSTANT indices only
// (no pointer casts into locals -> SROA promotes; the casts were R1-R3's
// scratch bug). The 20-element window carry-in comes from lane l-1 via
// __shfl_up, not LDS. No barriers anywhere.
__global__ __launch_bounds__(256) void k_feat(const float* __restrict__ prices,
                                              float* __restrict__ comb) {
    const int t = threadIdx.x;
    const int lane = t & 63, wv = t >> 6;
    const int b = blockIdx.x * 4 + wv;
    const float4* rowp4 = (const float4*)(prices + (size_t)b * SLEN);

    float x[64];
    #pragma unroll
    for (int i = 0; i < 16; ++i) {
        float4 v = rowp4[lane * 16 + i];
        x[4 * i]     = v.x;
        x[4 * i + 1] = v.y;
        x[4 * i + 2] = v.z;
        x[4 * i + 3] = v.w;
    }

    // o[j] = element (p0 - 20 + j)  == lane-1's x[44+j]; zero for lane 0 edge
    float o[20];
    #pragma unroll
    for (int j = 0; j < 20; ++j) {
        float v = __shfl_up(x[44 + j], 1);
        o[j] = (lane == 0) ? 0.0f : v;
    }

    // Winit = window ending at p0-1 (s[p0-20 .. p0-1]); uniform update after
    float W = 0.0f;
    #pragma unroll
    for (int j = 0; j < 20; ++j) W += o[j];

    const float p0f = (float)(lane * 64);
    float sum = 0.0f, sq = 0.0f, ts = 0.0f;
    #pragma unroll
    for (int j = 0; j < 64; ++j) {
        float xv = x[j];
        float old = (j < 20) ? o[j] : x[j - 20];   // compile-time select
        W += xv - old;                             // window now ends at p0+j
        sum += xv;
        sq = fmaf(xv, xv, sq);
        float c = fminf(p0f + (float)(j + 1), 20.0f);  // <20 only on lane 0 head
        float sm = W * __builtin_amdgcn_rcpf(c);
        ts += (xv - sm) * __builtin_amdgcn_rcpf(sm + EPS);
    }

    #pragma unroll
    for (int off = 32; off > 0; off >>= 1) {
        sum += __shfl_xor(sum, off);
        sq  += __shfl_xor(sq,  off);
        ts  += __shfl_xor(ts,  off);
    }
    float p_last = __shfl(x[63], 63);   // element 4095
    float p_m10  = __shfl(x[54], 63);   // element 4086

    if (lane == 0) {
        float mean = sum * (1.0f / 4096.0f);
        float var  = fmaxf((sq - 4096.0f * mean * mean) * (1.0f / 4095.0f), 0.0f);
        float4 c;
        c.x = ts * (1.0f / 4096.0f);
        c.y = (p_last - p_m10) / (p_m10 + EPS);
        c.z = (p_last - mean) / (mean + EPS);
        c.w = sqrtf(var) / (mean + EPS);
        *(float4*)(comb + (size_t)b * 4) = c;
    }
}

// ---------------- K2: encoder + LN + head (MFMA) + softmax ----------------
#define ROWS 32

__global__ __launch_bounds__(256) void k_head(
    const float* __restrict__ combg, float* __restrict__ out,
    const float* __restrict__ enc_w, const float* __restrict__ enc_b,
    const float* __restrict__ enc_g, const float* __restrict__ enc_bt,
    const float* __restrict__ w1, const float* __restrict__ b1,
    const float* __restrict__ w2, const float* __restrict__ b2)
{
    __shared__ float comb[ROWS][4];
    __shared__ short rfb[ROWS][264];   // bf16 rf tile, +8 pad
    __shared__ float hbuf[ROWS][68];   // padded

    const int t = threadIdx.x;
    const int r0 = blockIdx.x * ROWS;
    const int lane = t & 63, wave = t >> 6;
    const int l15 = lane & 15, q = lane >> 4;

    if (t < ROWS * 4)
        comb[t >> 2][t & 3] = combg[(size_t)(r0 + (t >> 2)) * 4 + (t & 3)];

    // B-frags: wave w owns cols [16w,16w+16); B layout n=lane&15, k=q*8+j per k-tile
    bf16x8 bfrag[8];
    #pragma unroll
    for (int kt = 0; kt < 8; ++kt) {
        #pragma unroll
        for (int j = 0; j < 8; ++j) {
            int k = kt * 32 + q * 8 + j;
            bfrag[kt][j] = f2bf(w1[k * 64 + wave * 16 + l15]);
        }
    }

    const float ew0 = enc_w[wave * 256 + lane];
    const float ew1v = enc_w[wave * 256 + 64 + lane];
    const float ew2v = enc_w[wave * 256 + 128 + lane];
    const float ew3v = enc_w[wave * 256 + 192 + lane];
    const float ebv = enc_b[t], egv = enc_g[t], btv = enc_bt[t];

    __syncthreads();

    // encoder + relu + LayerNorm (wave == e-group of 64)
    for (int r = 0; r < ROWS; ++r) {
        float4 cb = *(const float4*)comb[r];
        float v = fmaf(cb.x, ew0, fmaf(cb.y, ew1v, fmaf(cb.z, ew2v, fmaf(cb.w, ew3v, ebv))));
        v = fmaxf(v, 0.0f);
        float sm = v;
        #pragma unroll
        for (int off = 32; off > 0; off >>= 1) sm += __shfl_xor(sm, off);
        float mu = sm * (1.0f / 64.0f);
        float d = v - mu;
        float vs = d * d;
        #pragma unroll
        for (int off = 32; off > 0; off >>= 1) vs += __shfl_xor(vs, off);
        float y = fmaf(d * rsqrtf(vs * (1.0f / 64.0f) + LN_EPS), egv, btv);
        out[(size_t)(r0 + r) * 256 + t] = y;       // regime_features fp32
        rfb[r][t] = f2bf(y);
    }
    __syncthreads();

    // h = rf @ w1 via 16x16x32 bf16 MFMA; wave handles m-tiles {0,1} for its n-tile
    f32x4 acc0 = {0.f, 0.f, 0.f, 0.f}, acc1 = {0.f, 0.f, 0.f, 0.f};
    #pragma unroll
    for (int kt = 0; kt < 8; ++kt) {
        bf16x8 a0 = *(const bf16x8*)&rfb[l15][kt * 32 + q * 8];
        bf16x8 a1 = *(const bf16x8*)&rfb[16 + l15][kt * 32 + q * 8];
        acc0 = __builtin_amdgcn_mfma_f32_16x16x32_bf16(a0, bfrag[kt], acc0, 0, 0, 0);
        acc1 = __builtin_amdgcn_mfma_f32_16x16x32_bf16(a1, bfrag[kt], acc1, 0, 0, 0);
    }

    const int col = wave * 16 + l15;
    const float b1v = b1[col];
    #pragma unroll
    for (int rg = 0; rg < 4; ++rg) {
        hbuf[q * 4 + rg][col]      = fmaxf(acc0[rg] + b1v, 0.0f);
        hbuf[16 + q * 4 + rg][col] = fmaxf(acc1[rg] + b1v, 0.0f);
    }
    __syncthreads();

    // logits + softmax (quad per row)
    if (t < 128) {
        int r = t >> 2, c = t & 3;
        float lg = b2[c];
        #pragma unroll
        for (int j = 0; j < 64; ++j) lg = fmaf(hbuf[r][j], w2[j * 4 + c], lg);
        float mx = fmaxf(lg, __shfl_xor(lg, 1, 4));
        mx = fmaxf(mx, __shfl_xor(mx, 2, 4));
        float ex = __expf(lg - mx);
        float s2 = ex + __shfl_xor(ex, 1, 4);
        s2 += __shfl_xor(s2, 2, 4);
        out[PROBS_OFF + (size_t)(r0 + r) * 4 + c] = ex / s2;
    }
}

extern "C" void kernel_launch(void* const* d_in, const int* in_sizes, int n_in,
                              void* d_out, int out_size, void* d_ws, size_t ws_size,
                              hipStream_t stream) {
    const float* prices  = (const float*)d_in[0];
    const float* enc_w   = (const float*)d_in[1];
    const float* enc_b   = (const float*)d_in[2];
    const float* enc_g   = (const float*)d_in[3];
    const float* enc_bt  = (const float*)d_in[4];
    const float* head_w1 = (const float*)d_in[5];
    const float* head_b1 = (const float*)d_in[6];
    const float* head_w2 = (const float*)d_in[7];
    const float* head_b2 = (const float*)d_in[8];
    float* out  = (float*)d_out;
    float* comb = (float*)d_ws;    // 8192*4 floats staged in workspace

    k_feat<<<NROWS / 4, 256, 0, stream>>>(prices, comb);
    k_head<<<NROWS / ROWS, 256, 0, stream>>>(comb, out, enc_w, enc_b, enc_g, enc_bt,
                                             head_w1, head_b1, head_w2, head_b2);
}

// Round 6
// 221.370 us; speedup vs baseline: 1.0796x; 1.0796x over previous
//
#include <hip/hip_runtime.h>

#define EPS 1e-8f
#define LN_EPS 1e-5f
#define NROWS 8192
#define SLEN 4096
#define PROBS_OFF 2097152   // 8192*256

typedef __attribute__((ext_vector_type(8))) short bf16x8;
typedef __attribute__((ext_vector_type(4))) float f32x4;

__device__ __forceinline__ short f2bf(float f) {
    unsigned u = __float_as_uint(f);
    unsigned r = (u + 0x7FFFu + ((u >> 16) & 1u)) >> 16;  // RNE
    return (short)r;
}

// ---------------- K1: block-per-row, wide-LDS (b128), scratch-proof ----------------
// Coalesced float4 global loads (R5's strided loads cost +16us). LDS padded
// +4 floats per 16 => every 4-aligned float4 slot is contiguous AND 16B-aligned,
// so staging is 4 ds_write_b128 and the window is 9 ds_read_b128 (13 wide DS
// ops/thread vs R4's ~67 scalar ones). Window state in named scalars/float4s,
// constant indices only -- no pointer casts into locals (scratch bug of R1-R3).
#define SLP(i) ((i) + ((((i) >> 4)) << 2))

__global__ __launch_bounds__(256) void k_feat(const float* __restrict__ prices,
                                              float* __restrict__ comb) {
    __shared__ float sld[SLEN + (SLEN >> 2)];   // 5120 floats = 20 KB
    __shared__ float red[12];

    const int t = threadIdx.x;
    const int b = blockIdx.x;
    const int lane = t & 63, wv = t >> 6;
    const float4* rowp4 = (const float4*)(prices + (size_t)b * SLEN);

    // coalesced stage: thread t owns float4 m = i*256+t; SLP(4m) is 16B-aligned
    #pragma unroll
    for (int i = 0; i < 4; ++i) {
        int m = i * 256 + t;
        float4 v = rowp4[m];
        *(float4*)&sld[SLP(4 * m)] = v;
    }
    __syncthreads();

    // thread t owns positions [16t, 16t+16)
    const int p0 = t * 16;
    float4 s0 = *(const float4*)&sld[SLP(p0)];
    float4 s1 = *(const float4*)&sld[SLP(p0 + 4)];
    float4 s2 = *(const float4*)&sld[SLP(p0 + 8)];
    float4 s3 = *(const float4*)&sld[SLP(p0 + 12)];
    float4 q0, q1, q2, q3, q4;                  // s[p0-20 .. p0), zero-padded
    if (t > 0) {
        q0 = *(const float4*)&sld[SLP(p0 - 20)];
        q1 = *(const float4*)&sld[SLP(p0 - 16)];
        q2 = *(const float4*)&sld[SLP(p0 - 12)];
        q3 = *(const float4*)&sld[SLP(p0 - 8)];
        q4 = *(const float4*)&sld[SLP(p0 - 4)];
    } else {
        q0 = q1 = q2 = q3 = q4 = make_float4(0.f, 0.f, 0.f, 0.f);
    }

    // constant-index views (no casts, SROA-safe)
    float xv[16] = { s0.x, s0.y, s0.z, s0.w, s1.x, s1.y, s1.z, s1.w,
                     s2.x, s2.y, s2.z, s2.w, s3.x, s3.y, s3.z, s3.w };
    float ov[16] = { q0.x, q0.y, q0.z, q0.w, q1.x, q1.y, q1.z, q1.w,
                     q2.x, q2.y, q2.z, q2.w, q3.x, q3.y, q3.z, q3.w };

    // W_pre = window ending at p0-1 = sum s[p0-19 .. p0-1] (19 terms)
    float W = q0.y + q0.z + q0.w
            + q1.x + q1.y + q1.z + q1.w
            + q2.x + q2.y + q2.z + q2.w
            + q3.x + q3.y + q3.z + q3.w
            + q4.x + q4.y + q4.z + q4.w;

    float sum = 0.0f, sq = 0.0f, ts = 0.0f;
    #pragma unroll
    for (int j = 0; j < 16; ++j) {
        float x = xv[j];
        W += (j == 0) ? x : (x - ov[j]);        // window now ends at p0+j
        sum += x;
        sq = fmaf(x, x, sq);
        float c = fminf((float)(p0 + j + 1), 20.0f);
        float sm = W * __builtin_amdgcn_rcpf(c);
        ts += (x - sm) * __builtin_amdgcn_rcpf(sm + EPS);
    }

    #pragma unroll
    for (int off = 32; off > 0; off >>= 1) {
        sum += __shfl_xor(sum, off);
        sq  += __shfl_xor(sq,  off);
        ts  += __shfl_xor(ts,  off);
    }
    if (lane == 0) { red[wv * 3] = sum; red[wv * 3 + 1] = sq; red[wv * 3 + 2] = ts; }
    __syncthreads();

    if (t == 0) {
        float S = red[0] + red[3] + red[6] + red[9];
        float Q = red[1] + red[4] + red[7] + red[10];
        float T = red[2] + red[5] + red[8] + red[11];
        float mean = S * (1.0f / 4096.0f);
        float var  = fmaxf((Q - 4096.0f * mean * mean) * (1.0f / 4095.0f), 0.0f);
        float p_last = sld[SLP(4095)];
        float p_m10  = sld[SLP(4086)];
        float4 c;
        c.x = T * (1.0f / 4096.0f);
        c.y = (p_last - p_m10) / (p_m10 + EPS);
        c.z = (p_last - mean) / (mean + EPS);
        c.w = sqrtf(var) / (mean + EPS);
        *(float4*)(comb + (size_t)b * 4) = c;
    }
}

// ---------------- K2: encoder + LN + head (MFMA) + softmax ----------------
#define ROWS 32

__global__ __launch_bounds__(256) void k_head(
    const float* __restrict__ combg, float* __restrict__ out,
    const float* __restrict__ enc_w, const float* __restrict__ enc_b,
    const float* __restrict__ enc_g, const float* __restrict__ enc_bt,
    const float* __restrict__ w1, const float* __restrict__ b1,
    const float* __restrict__ w2, const float* __restrict__ b2)
{
    __shared__ float comb[ROWS][4];
    __shared__ short rfb[ROWS][264];   // bf16 rf tile, +8 pad
    __shared__ float hbuf[ROWS][68];   // padded

    const int t = threadIdx.x;
    const int r0 = blockIdx.x * ROWS;
    const int lane = t & 63, wave = t >> 6;
    const int l15 = lane & 15, q = lane >> 4;

    if (t < ROWS * 4)
        comb[t >> 2][t & 3] = combg[(size_t)(r0 + (t >> 2)) * 4 + (t & 3)];

    // B-frags: wave w owns cols [16w,16w+16); B layout n=lane&15, k=q*8+j per k-tile
    bf16x8 bfrag[8];
    #pragma unroll
    for (int kt = 0; kt < 8; ++kt) {
        #pragma unroll
        for (int j = 0; j < 8; ++j) {
            int k = kt * 32 + q * 8 + j;
            bfrag[kt][j] = f2bf(w1[k * 64 + wave * 16 + l15]);
        }
    }

    const float ew0 = enc_w[wave * 256 + lane];
    const float ew1v = enc_w[wave * 256 + 64 + lane];
    const float ew2v = enc_w[wave * 256 + 128 + lane];
    const float ew3v = enc_w[wave * 256 + 192 + lane];
    const float ebv = enc_b[t], egv = enc_g[t], btv = enc_bt[t];

    __syncthreads();

    // encoder + relu + LayerNorm (wave == e-group of 64)
    for (int r = 0; r < ROWS; ++r) {
        float4 cb = *(const float4*)comb[r];
        float v = fmaf(cb.x, ew0, fmaf(cb.y, ew1v, fmaf(cb.z, ew2v, fmaf(cb.w, ew3v, ebv))));
        v = fmaxf(v, 0.0f);
        float sm = v;
        #pragma unroll
        for (int off = 32; off > 0; off >>= 1) sm += __shfl_xor(sm, off);
        float mu = sm * (1.0f / 64.0f);
        float d = v - mu;
        float vs = d * d;
        #pragma unroll
        for (int off = 32; off > 0; off >>= 1) vs += __shfl_xor(vs, off);
        float y = fmaf(d * rsqrtf(vs * (1.0f / 64.0f) + LN_EPS), egv, btv);
        out[(size_t)(r0 + r) * 256 + t] = y;       // regime_features fp32
        rfb[r][t] = f2bf(y);
    }
    __syncthreads();

    // h = rf @ w1 via 16x16x32 bf16 MFMA; wave handles m-tiles {0,1} for its n-tile
    f32x4 acc0 = {0.f, 0.f, 0.f, 0.f}, acc1 = {0.f, 0.f, 0.f, 0.f};
    #pragma unroll
    for (int kt = 0; kt < 8; ++kt) {
        bf16x8 a0 = *(const bf16x8*)&rfb[l15][kt * 32 + q * 8];
        bf16x8 a1 = *(const bf16x8*)&rfb[16 + l15][kt * 32 + q * 8];
        acc0 = __builtin_amdgcn_mfma_f32_16x16x32_bf16(a0, bfrag[kt], acc0, 0, 0, 0);
        acc1 = __builtin_amdgcn_mfma_f32_16x16x32_bf16(a1, bfrag[kt], acc1, 0, 0, 0);
    }

    const int col = wave * 16 + l15;
    const float b1v = b1[col];
    #pragma unroll
    for (int rg = 0; rg < 4; ++rg) {
        hbuf[q * 4 + rg][col]      = fmaxf(acc0[rg] + b1v, 0.0f);
        hbuf[16 + q * 4 + rg][col] = fmaxf(acc1[rg] + b1v, 0.0f);
    }
    __syncthreads();

    // logits + softmax (quad per row)
    if (t < 128) {
        int r = t >> 2, c = t & 3;
        float lg = b2[c];
        #pragma unroll
        for (int j = 0; j < 64; ++j) lg = fmaf(hbuf[r][j], w2[j * 4 + c], lg);
        float mx = fmaxf(lg, __shfl_xor(lg, 1, 4));
        mx = fmaxf(mx, __shfl_xor(mx, 2, 4));
        float ex = __expf(lg - mx);
        float s2 = ex + __shfl_xor(ex, 1, 4);
        s2 += __shfl_xor(s2, 2, 4);
        out[PROBS_OFF + (size_t)(r0 + r) * 4 + c] = ex / s2;
    }
}

extern "C" void kernel_launch(void* const* d_in, const int* in_sizes, int n_in,
                              void* d_out, int out_size, void* d_ws, size_t ws_size,
                              hipStream_t stream) {
    const float* prices  = (const float*)d_in[0];
    const float* enc_w   = (const float*)d_in[1];
    const float* enc_b   = (const float*)d_in[2];
    const float* enc_g   = (const float*)d_in[3];
    const float* enc_bt  = (const float*)d_in[4];
    const float* head_w1 = (const float*)d_in[5];
    const float* head_b1 = (const float*)d_in[6];
    const float* head_w2 = (const float*)d_in[7];
    const float* head_b2 = (const float*)d_in[8];
    float* out  = (float*)d_out;
    float* comb = (float*)d_ws;    // 8192*4 floats staged in workspace

    k_feat<<<NROWS, 256, 0, stream>>>(prices, comb);
    k_head<<<NROWS / ROWS, 256, 0, stream>>>(comb, out, enc_w, enc_b, enc_g, enc_bt,
                                             head_w1, head_b1, head_w2, head_b2);
}

// Round 7
// 221.129 us; speedup vs baseline: 1.0808x; 1.0011x over previous
//
#include <hip/hip_runtime.h>

#define EPS 1e-8f
#define LN_EPS 1e-5f
#define NROWS 8192
#define SLEN 4096
#define PROBS_OFF 2097152   // 8192*256

typedef __attribute__((ext_vector_type(8))) short bf16x8;
typedef __attribute__((ext_vector_type(4))) float f32x4;

__device__ __forceinline__ short f2bf(float f) {
    unsigned u = __float_as_uint(f);
    unsigned r = (u + 0x7FFFu + ((u >> 16) & 1u)) >> 16;  // RNE
    return (short)r;
}

// pad 4 floats per 16: 4-aligned float4 slots stay contiguous and 16B-aligned
#define SLP(i) ((i) + ((((i) >> 4)) << 2))

// ---------------- K1: 2 blocks per row, partial reductions into ws ----------------
// Block (b,h) stages positions [2048h-32, 2048h+2048) of row b (32-float halo
// carries the rolling-20 window across the split; h=0 halo staged as zeros so
// the row edge stays branch-free). Writes partial S,Q,T to ws[b*8+3h..]; h=1
// tail threads stash p_m10/p_last at ws[b*8+6,7]. ws combine happens in k_head.
__global__ __launch_bounds__(256) void k_feat(const float* __restrict__ prices,
                                              float* __restrict__ ws) {
    __shared__ float sld[2596];   // SLP(2079)=2595; 10.4 KB
    __shared__ float red[12];

    const int t = threadIdx.x;
    const int b = blockIdx.x >> 1, h = blockIdx.x & 1;
    const int lane = t & 63, wv = t >> 6;
    const float4* rowp4 = (const float4*)(prices + (size_t)b * SLEN);

    // stage 520 float4 slots: f = t, t+256, (t<8: 512+t); global f4 index g = 512h-8+f
    {
        int f0 = t, f1 = t + 256;
        int g0 = 512 * h - 8 + f0, g1 = 512 * h - 8 + f1;
        float4 v0 = (g0 >= 0) ? rowp4[g0] : make_float4(0.f, 0.f, 0.f, 0.f);
        float4 v1 = rowp4[g1];                       // g1 >= 248 always
        *(float4*)&sld[SLP(4 * f0)] = v0;
        *(float4*)&sld[SLP(4 * f1)] = v1;
        if (t < 8) {
            int f2 = 512 + t;
            *(float4*)&sld[SLP(4 * f2)] = rowp4[512 * h - 8 + f2];
        }
    }
    __syncthreads();

    // thread t owns local positions [32+8t, 32+8t+8)  (global p = 2048h + 8t + j)
    const int li0 = 32 + 8 * t;
    float4 s0 = *(const float4*)&sld[SLP(li0)];
    float4 s1 = *(const float4*)&sld[SLP(li0 + 4)];
    float4 q0 = *(const float4*)&sld[SLP(li0 - 20)];
    float4 q1 = *(const float4*)&sld[SLP(li0 - 16)];
    float4 q2 = *(const float4*)&sld[SLP(li0 - 12)];
    float4 q3 = *(const float4*)&sld[SLP(li0 - 8)];
    float4 q4 = *(const float4*)&sld[SLP(li0 - 4)];

    // constant-index views (SROA-safe: no pointer casts into locals)
    float xv[8] = { s0.x, s0.y, s0.z, s0.w, s1.x, s1.y, s1.z, s1.w };
    float ov[8] = { q0.x, q0.y, q0.z, q0.w, q1.x, q1.y, q1.z, q1.w };

    // window ending at p-1: 19 preceding values (staged zeros cover the row head)
    float W = q0.y + q0.z + q0.w
            + q1.x + q1.y + q1.z + q1.w
            + q2.x + q2.y + q2.z + q2.w
            + q3.x + q3.y + q3.z + q3.w
            + q4.x + q4.y + q4.z + q4.w;

    const float pf = (float)(2048 * h + 8 * t);
    float sum = 0.0f, sq = 0.0f, ts = 0.0f;
    #pragma unroll
    for (int j = 0; j < 8; ++j) {
        float x = xv[j];
        W += (j == 0) ? x : (x - ov[j]);
        sum += x;
        sq = fmaf(x, x, sq);
        float c = fminf(pf + (float)(j + 1), 20.0f);
        float sm = W * __builtin_amdgcn_rcpf(c);
        ts += (x - sm) * __builtin_amdgcn_rcpf(sm + EPS);
    }

    // tail values (h=1 only): pos 4086 = t254.xv[6], pos 4095 = t255.xv[7]
    if (h == 1 && t == 254) ws[(size_t)b * 8 + 6] = xv[6];
    if (h == 1 && t == 255) ws[(size_t)b * 8 + 7] = xv[7];

    #pragma unroll
    for (int off = 32; off > 0; off >>= 1) {
        sum += __shfl_xor(sum, off);
        sq  += __shfl_xor(sq,  off);
        ts  += __shfl_xor(ts,  off);
    }
    if (lane == 0) { red[wv * 3] = sum; red[wv * 3 + 1] = sq; red[wv * 3 + 2] = ts; }
    __syncthreads();

    if (t == 0) {
        float S = red[0] + red[3] + red[6] + red[9];
        float Q = red[1] + red[4] + red[7] + red[10];
        float T = red[2] + red[5] + red[8] + red[11];
        float* wp = ws + (size_t)b * 8 + 3 * h;
        wp[0] = S; wp[1] = Q; wp[2] = T;
    }
}

// ---------------- K2: combine + encoder + LN + head (MFMA) + softmax ----------------
#define ROWS 32

__global__ __launch_bounds__(256) void k_head(
    const float* __restrict__ ws, float* __restrict__ out,
    const float* __restrict__ enc_w, const float* __restrict__ enc_b,
    const float* __restrict__ enc_g, const float* __restrict__ enc_bt,
    const float* __restrict__ w1, const float* __restrict__ b1,
    const float* __restrict__ w2, const float* __restrict__ b2)
{
    __shared__ float comb[ROWS][4];
    __shared__ short rfb[ROWS][264];   // bf16 rf tile, +8 pad
    __shared__ float hbuf[ROWS][68];   // padded

    const int t = threadIdx.x;
    const int r0 = blockIdx.x * ROWS;
    const int lane = t & 63, wave = t >> 6;
    const int l15 = lane & 15, q = lane >> 4;

    // combine half-row partials -> 4 features per row
    if (t < ROWS) {
        const float* wp = ws + (size_t)(r0 + t) * 8;
        float4 a = *(const float4*)wp;         // S0,Q0,T0,S1
        float4 bb = *(const float4*)(wp + 4);  // Q1,T1,p_m10,p_last
        float S = a.x + a.w, Q = a.y + bb.x, T = a.z + bb.y;
        float p_m10 = bb.z, p_last = bb.w;
        float mean = S * (1.0f / 4096.0f);
        float var  = fmaxf((Q - 4096.0f * mean * mean) * (1.0f / 4095.0f), 0.0f);
        comb[t][0] = T * (1.0f / 4096.0f);
        comb[t][1] = (p_last - p_m10) / (p_m10 + EPS);
        comb[t][2] = (p_last - mean) / (mean + EPS);
        comb[t][3] = sqrtf(var) / (mean + EPS);
    }

    // B-frags: wave w owns cols [16w,16w+16); B layout n=lane&15, k=q*8+j per k-tile
    bf16x8 bfrag[8];
    #pragma unroll
    for (int kt = 0; kt < 8; ++kt) {
        #pragma unroll
        for (int j = 0; j < 8; ++j) {
            int k = kt * 32 + q * 8 + j;
            bfrag[kt][j] = f2bf(w1[k * 64 + wave * 16 + l15]);
        }
    }

    const float ew0 = enc_w[wave * 256 + lane];
    const float ew1v = enc_w[wave * 256 + 64 + lane];
    const float ew2v = enc_w[wave * 256 + 128 + lane];
    const float ew3v = enc_w[wave * 256 + 192 + lane];
    const float ebv = enc_b[t], egv = enc_g[t], btv = enc_bt[t];

    __syncthreads();

    // encoder + relu + LayerNorm (wave == e-group of 64)
    for (int r = 0; r < ROWS; ++r) {
        float4 cb = *(const float4*)comb[r];
        float v = fmaf(cb.x, ew0, fmaf(cb.y, ew1v, fmaf(cb.z, ew2v, fmaf(cb.w, ew3v, ebv))));
        v = fmaxf(v, 0.0f);
        float sm = v;
        #pragma unroll
        for (int off = 32; off > 0; off >>= 1) sm += __shfl_xor(sm, off);
        float mu = sm * (1.0f / 64.0f);
        float d = v - mu;
        float vs = d * d;
        #pragma unroll
        for (int off = 32; off > 0; off >>= 1) vs += __shfl_xor(vs, off);
        float y = fmaf(d * rsqrtf(vs * (1.0f / 64.0f) + LN_EPS), egv, btv);
        out[(size_t)(r0 + r) * 256 + t] = y;       // regime_features fp32
        rfb[r][t] = f2bf(y);
    }
    __syncthreads();

    // h = rf @ w1 via 16x16x32 bf16 MFMA; wave handles m-tiles {0,1} for its n-tile
    f32x4 acc0 = {0.f, 0.f, 0.f, 0.f}, acc1 = {0.f, 0.f, 0.f, 0.f};
    #pragma unroll
    for (int kt = 0; kt < 8; ++kt) {
        bf16x8 a0 = *(const bf16x8*)&rfb[l15][kt * 32 + q * 8];
        bf16x8 a1 = *(const bf16x8*)&rfb[16 + l15][kt * 32 + q * 8];
        acc0 = __builtin_amdgcn_mfma_f32_16x16x32_bf16(a0, bfrag[kt], acc0, 0, 0, 0);
        acc1 = __builtin_amdgcn_mfma_f32_16x16x32_bf16(a1, bfrag[kt], acc1, 0, 0, 0);
    }

    const int col = wave * 16 + l15;
    const float b1v = b1[col];
    #pragma unroll
    for (int rg = 0; rg < 4; ++rg) {
        hbuf[q * 4 + rg][col]      = fmaxf(acc0[rg] + b1v, 0.0f);
        hbuf[16 + q * 4 + rg][col] = fmaxf(acc1[rg] + b1v, 0.0f);
    }
    __syncthreads();

    // logits + softmax (quad per row)
    if (t < 128) {
        int r = t >> 2, c = t & 3;
        float lg = b2[c];
        #pragma unroll
        for (int j = 0; j < 64; ++j) lg = fmaf(hbuf[r][j], w2[j * 4 + c], lg);
        float mx = fmaxf(lg, __shfl_xor(lg, 1, 4));
        mx = fmaxf(mx, __shfl_xor(mx, 2, 4));
        float ex = __expf(lg - mx);
        float s2 = ex + __shfl_xor(ex, 1, 4);
        s2 += __shfl_xor(s2, 2, 4);
        out[PROBS_OFF + (size_t)(r0 + r) * 4 + c] = ex / s2;
    }
}

extern "C" void kernel_launch(void* const* d_in, const int* in_sizes, int n_in,
                              void* d_out, int out_size, void* d_ws, size_t ws_size,
                              hipStream_t stream) {
    const float* prices  = (const float*)d_in[0];
    const float* enc_w   = (const float*)d_in[1];
    const float* enc_b   = (const float*)d_in[2];
    const float* enc_g   = (const float*)d_in[3];
    const float* enc_bt  = (const float*)d_in[4];
    const float* head_w1 = (const float*)d_in[5];
    const float* head_b1 = (const float*)d_in[6];
    const float* head_w2 = (const float*)d_in[7];
    const float* head_b2 = (const float*)d_in[8];
    float* out = (float*)d_out;
    float* ws  = (float*)d_ws;    // 8192 rows x 8 floats of partials

    k_feat<<<NROWS * 2, 256, 0, stream>>>(prices, ws);
    k_head<<<NROWS / ROWS, 256, 0, stream>>>(ws, out, enc_w, enc_b, enc_g, enc_bt,
                                             head_w1, head_b1, head_w2, head_b2);
}